// Round 4
// baseline (474.059 us; speedup 1.0000x reference)
//
#include <hip/hip_runtime.h>
#include <stdint.h>

// Problem constants
#define NN   16
#define HH   112
#define WW   112
#define CIN  256
#define COUT 256
#define HP   114          // padded height
#define WP   114          // padded width
#define M_TOTAL (NN * HH * WW)                    // 200704
#define XP_BYTES ((size_t)NN * HP * WP * CIN)     // 53,231,616
#define WPK_BYTES ((size_t)9 * COUT * CIN)        // 589,824 (fragment-ordered)

typedef int v4i __attribute__((ext_vector_type(4)));

__device__ __forceinline__ void load_lds16(const void* g, void* l) {
  __builtin_amdgcn_global_load_lds(
      (const __attribute__((address_space(1))) void*)g,
      (__attribute__((address_space(3))) void*)l, 16, 0, 0);
}

// register-only byte pack: 4 ints (int8-valued) -> one dword
__device__ __forceinline__ int pack4(int a, int b, int c, int d) {
  return (a & 255) | ((b & 255) << 8) | ((c & 255) << 16) | (d << 24);
}

// ---------------- fused pack: x (blocks 0..12543), weight (12544..13119), border (13120..13571)
__global__ __launch_bounds__(256) void pack_all_kernel(const int* __restrict__ x,
                                                       const int* __restrict__ wgt,
                                                       char* __restrict__ xp,
                                                       char* __restrict__ wp) {
  int bid = blockIdx.x;
  if (bid < 12544) {
    // pack x: one thread per 16 ints -> one 16B packed store
    int t = bid * 256 + threadIdx.x;          // M_TOTAL*16 threads
    int g = t & 15;
    int p = t >> 4;
    int w = p % WW;
    int t2 = p / WW;
    int h = t2 % HH;
    int n = t2 / HH;
    const int4* src = (const int4*)(x + (size_t)t * 16);
    int4 a = src[0], b = src[1], c = src[2], d = src[3];
    int4 ov;
    ov.x = pack4(a.x, a.y, a.z, a.w);
    ov.y = pack4(b.x, b.y, b.z, b.w);
    ov.z = pack4(c.x, c.y, c.z, c.w);
    ov.w = pack4(d.x, d.y, d.z, d.w);
    size_t dst = (((size_t)n * HP + (h + 1)) * WP + (w + 1)) * CIN + (size_t)g * 16;
    *(int4*)(xp + dst) = ov;
  } else if (bid < 12544 + 576) {
    // pack weight into FRAGMENT order:
    // for (tap, kb, jg): 1024B block; byte at lane l (l = ((ci>>4)&3)*16 + (cout&15)),
    // offset l*16 + (ci&15), where cout = jg*16 + (cout&15), ci = kb*64 + (l>>4)*16 + (ci&15).
    // A wave's dwordx4 at block + lane*16 is then exactly the MFMA B-fragment.
    int t = (bid - 12544) * 256 + threadIdx.x;   // 2304*64 threads, 4 ints each
    int i = t * 4;                               // wgt linear int index
    int cout = i / 2304;                         // 2304 ints per cout (9 taps * 256 ci)
    int rem = i - cout * 2304;
    int tap = rem >> 8;
    int ci = rem & 255;                          // 4-aligned
    int4 v = *(const int4*)(wgt + (size_t)i);
    int ov = pack4(v.x, v.y, v.z, v.w);
    int kb = ci >> 6;
    int jg = cout >> 4;
    int l = ((ci >> 4) & 3) * 16 + (cout & 15);
    size_t dst = (((size_t)(tap * 4 + kb) * 16 + jg) * 1024) + (size_t)l * 16 + (ci & 15);
    *(int*)(wp + dst) = ov;
  } else {
    // zero the 1-pixel border of xp
    int t = (bid - 13120) * 256 + threadIdx.x;   // 452*256 threads
    int g = t & 15;
    int pix = t >> 4;                            // 0..7231
    int n = pix / 452;
    int b = pix % 452;
    int h, w;
    if (b < 114) { h = 0; w = b; }
    else if (b < 228) { h = 113; w = b - 114; }
    else { int r = b - 228; h = 1 + (r >> 1); w = (r & 1) ? 113 : 0; }
    size_t dst = (((size_t)n * HP + h) * WP + w) * CIN + (size_t)g * 16;
    *(int4*)(xp + dst) = make_int4(0, 0, 0, 0);
  }
}

// ---------------- implicit-GEMM conv: C[M=200704][256] = A[M][2304] * B[2304][256] ----------------
// Tile 128x256, 256 threads / 4 waves (2m x 2n); per wave 64m x 128n = 4x8 MFMA
// 16x16x64 i8 tiles (32 MFMA/step, BK=64).
// A: LDS, QUADRUPLE-buffered (4 x 8 KB = 32 KB), staged 2 steps ahead via
//    global_load_lds (2 chunks/thread/step). XOR-swizzled columns (0 conflicts).
// B: NO LDS — fragment-ordered global loads (coalesced 1KB/wave dwordx4) straight
//    to VGPRs from the 576KB L2-resident repacked weights, loaded at step top and
//    compiler-waited (vmcnt) just before the MFMA cluster.
// Per step: ONE barrier, ONE manual counted vmcnt(2) (leaves the A(u+2) stage in
// flight across the barrier). 32 KB LDS -> 2 blocks/CU: cross-block overlap fills
// each block's read/wait windows (matrix pipe is the designed bottleneck).
__global__ __launch_bounds__(256, 2) void conv_mfma_kernel(const char* __restrict__ xp,
                                                           const char* __restrict__ wp2,
                                                           int* __restrict__ out) {
  __shared__ __align__(16) char As[4 * 8192];   // 32 KB
  const int tid = threadIdx.x;
  const int lane = tid & 63;
  const int wave = tid >> 6;
  const int mtile = blockIdx.x;
  const int wm = wave & 1;   // m half (64 rows)
  const int wn = wave >> 1;  // n half (128 cols)

  // ---- A staging sources: 2 chunks of 1KB per wave per step ----
  // LDS tile: [128 rows][4 x 16B cols], position (row,c) holds global col (c ^ ((row>>1)&3)).
  const char* gsrcA[2];
#pragma unroll
  for (int q = 0; q < 2; q++) {
    int p = wave * 2048 + q * 1024 + lane * 16;    // LDS linear byte pos
    int row = p >> 6;
    int colg = ((p >> 4) & 3) ^ ((row >> 1) & 3);
    int m = mtile * 128 + row;
    int w = m % WW;
    int t2 = m / WW;
    int h = t2 % HH;
    int n = t2 / HH;
    gsrcA[q] = xp + (((size_t)n * HP + h) * WP + w) * CIN + (size_t)colg * 16;
  }

  // ---- B fragment base: frag j of step s at bptr + s*16384 + j*1024 ----
  const char* bptr = wp2 + (size_t)(wn * 8) * 1024 + (size_t)lane * 16;

  // ---- A fragment LDS offsets (within one 8KB buffer) ----
  int aoff[4];
#pragma unroll
  for (int i = 0; i < 4; i++) {
    int r = wm * 64 + i * 16 + (lane & 15);
    aoff[i] = r * 64 + (((lane >> 4) ^ ((r >> 1) & 3)) * 16);
  }

  v4i acc[4][8];
#pragma unroll
  for (int i = 0; i < 4; i++)
#pragma unroll
    for (int j = 0; j < 8; j++) acc[i][j] = (v4i){0, 0, 0, 0};

  // stage A for step s into buffer buf
  auto stageA = [&](int s, int buf) {
    int tap = s >> 2;
    int kb = s & 3;
    int ky = tap / 3;
    int kx = tap - ky * 3;
    int off = (ky * WP + kx) * CIN + kb * 64;
    load_lds16(gsrcA[0] + off, As + buf * 8192 + wave * 2048);
    load_lds16(gsrcA[1] + off, As + buf * 8192 + wave * 2048 + 1024);
  };

  // prologue: A(0)->buf0, A(1)->buf1; vmcnt(2) retires A(0), leaves A(1) in flight
  stageA(0, 0);
  stageA(1, 1);
  asm volatile("s_waitcnt vmcnt(2)" ::: "memory");
  __builtin_amdgcn_s_barrier();

// one K-step. BUF = u%4; SB = absolute step (B offsets); stage A(u+2) -> SBUF.
// vm queue entering: [A(u+1):2]. Issue B(u):8 then A(u+2):2 (order pinned by
// sched_barrier). Compiler emits vmcnt(2) before MFMA (retires A(u+1)+B(u),
// leaves A(u+2)); our end-of-step vmcnt is then free. lgkm wait for af is
// compiler-inserted via the af->MFMA dependence.
#define CONV_STEP(BUF, SB, DOSTAGE, SOA, SBUF, VMN)                                 \
  {                                                                                 \
    const char* Ab = As + (BUF) * 8192;                                             \
    v4i bf[8];                                                                      \
    _Pragma("unroll") for (int j = 0; j < 8; j++)                                   \
        bf[j] = *(const v4i*)(bptr + (size_t)(SB) * 16384 + j * 1024);              \
    v4i af[4];                                                                      \
    _Pragma("unroll") for (int i = 0; i < 4; i++)                                   \
        af[i] = *(const v4i*)(Ab + aoff[i]);                                        \
    __builtin_amdgcn_sched_barrier(0);                                              \
    if (DOSTAGE) {                                                                  \
      load_lds16(gsrcA[0] + (SOA), As + (SBUF) * 8192 + wave * 2048);               \
      load_lds16(gsrcA[1] + (SOA), As + (SBUF) * 8192 + wave * 2048 + 1024);        \
    }                                                                               \
    __builtin_amdgcn_s_setprio(1);                                                  \
    _Pragma("unroll") for (int i = 0; i < 4; i++)                                   \
      _Pragma("unroll") for (int j = 0; j < 8; j++)                                 \
        acc[i][j] = __builtin_amdgcn_mfma_i32_16x16x64_i8(af[i], bf[j],             \
                                                          acc[i][j], 0, 0, 0);      \
    __builtin_amdgcn_s_setprio(0);                                                  \
    asm volatile("s_waitcnt vmcnt(" VMN ")" ::: "memory");                          \
    __builtin_amdgcn_s_barrier();                                                   \
  }

  // main loop: groups g=0..7 cover steps 0..31; stage targets u+2 (<= 33)
#pragma unroll 1
  for (int g = 0; g < 8; g++) {
    int ky0 = g / 3, kx0 = g - ky0 * 3;
    int oA0 = (ky0 * WP + kx0) * CIN;            // tap g
    int ky1 = (g + 1) / 3, kx1 = (g + 1) - ky1 * 3;
    int oA1 = (ky1 * WP + kx1) * CIN;            // tap g+1
    int sb = 4 * g;
    CONV_STEP(0, sb + 0, true, oA0 + 128, 2, "2")   // stage A(4g+2): tap g, kb2
    CONV_STEP(1, sb + 1, true, oA0 + 192, 3, "2")   // stage A(4g+3): tap g, kb3
    CONV_STEP(2, sb + 2, true, oA1 + 0,   0, "2")   // stage A(4g+4): tap g+1, kb0
    CONV_STEP(3, sb + 3, true, oA1 + 64,  1, "2")   // stage A(4g+5): tap g+1, kb1
  }
  // peeled tail: steps 32..35 (tap 8)
  {
    int oA8 = (2 * WP + 2) * CIN;
    CONV_STEP(0, 32, true,  oA8 + 128, 2, "2")      // stage A(34): tap8 kb2
    CONV_STEP(1, 33, true,  oA8 + 192, 3, "2")      // stage A(35): tap8 kb3
    CONV_STEP(2, 34, false, 0, 0, "0")
    CONV_STEP(3, 35, false, 0, 0, "0")
  }
#undef CONV_STEP

  // ---- epilogue: C/D layout col=lane&15, row=(lane>>4)*4+reg ----
#pragma unroll
  for (int i = 0; i < 4; i++) {
    const int mg = mtile * 128 + wm * 64 + i * 16 + ((lane >> 4) * 4);
#pragma unroll
    for (int r = 0; r < 4; r++) {
      int* orow = out + (size_t)(mg + r) * COUT + wn * 128 + (lane & 15);
#pragma unroll
      for (int j = 0; j < 8; j++) orow[j * 16] = acc[i][j][r];
    }
  }
}

// ---------------- fallback (only if ws too small): direct int32 conv ----------------
__global__ void conv_naive_kernel(const int* __restrict__ x, const int* __restrict__ wgt,
                                  int* __restrict__ out, int total) {
  int idx = blockIdx.x * 256 + threadIdx.x;
  if (idx >= total) return;
  int co = idx & 255;
  int p = idx >> 8;
  int w = p % WW;
  int t2 = p / WW;
  int h = t2 % HH;
  int n = t2 / HH;
  int acc = 0;
  for (int ky = 0; ky < 3; ky++) {
    int ih = h + ky - 1;
    if (ih < 0 || ih >= HH) continue;
    for (int kx = 0; kx < 3; kx++) {
      int iw = w + kx - 1;
      if (iw < 0 || iw >= WW) continue;
      const int* xs = x + (((size_t)n * HH + ih) * WW + iw) * CIN;
      const int* ws = wgt + ((size_t)co * 9 + ky * 3 + kx) * CIN;
      for (int ci = 0; ci < CIN; ci++) acc += xs[ci] * ws[ci];
    }
  }
  out[idx] = acc;
}

extern "C" void kernel_launch(void* const* d_in, const int* in_sizes, int n_in,
                              void* d_out, int out_size, void* d_ws, size_t ws_size,
                              hipStream_t stream) {
  const int* x = (const int*)d_in[0];
  const int* wgt = (const int*)d_in[1];
  int* out = (int*)d_out;
  const size_t need = XP_BYTES + WPK_BYTES;
  if (ws_size >= need) {
    char* xp = (char*)d_ws;
    char* wp = xp + XP_BYTES;
    pack_all_kernel<<<13572, 256, 0, stream>>>(x, wgt, xp, wp);
    conv_mfma_kernel<<<M_TOTAL / 128, 256, 0, stream>>>(xp, wp, out);   // 1568 blocks
  } else {
    conv_naive_kernel<<<(out_size + 255) / 256, 256, 0, stream>>>(x, wgt, out, out_size);
  }
}

// Round 5
// 459.234 us; speedup vs baseline: 1.0323x; 1.0323x over previous
//
#include <hip/hip_runtime.h>
#include <stdint.h>

// Problem constants
#define NN   16
#define HH   112
#define WW   112
#define CIN  256
#define COUT 256
#define HP   114          // padded height
#define WP   114          // padded width
#define M_TOTAL (NN * HH * WW)                    // 200704
#define XP_BYTES ((size_t)NN * HP * WP * CIN)     // 53,231,616
#define WPK_BYTES ((size_t)9 * COUT * CIN)        // 589,824 (fragment-ordered)

typedef int v4i __attribute__((ext_vector_type(4)));

__device__ __forceinline__ void load_lds16(const void* g, void* l) {
  __builtin_amdgcn_global_load_lds(
      (const __attribute__((address_space(1))) void*)g,
      (__attribute__((address_space(3))) void*)l, 16, 0, 0);
}

// register-only byte pack: 4 ints (int8-valued) -> one dword
__device__ __forceinline__ int pack4(int a, int b, int c, int d) {
  return (a & 255) | ((b & 255) << 8) | ((c & 255) << 16) | (d << 24);
}

// ---------------- fused pack: x (blocks 0..12543), weight (12544..13119), border (13120..13571)
__global__ __launch_bounds__(256) void pack_all_kernel(const int* __restrict__ x,
                                                       const int* __restrict__ wgt,
                                                       char* __restrict__ xp,
                                                       char* __restrict__ wp) {
  int bid = blockIdx.x;
  if (bid < 12544) {
    // pack x: one thread per 16 ints -> one 16B packed store
    int t = bid * 256 + threadIdx.x;          // M_TOTAL*16 threads
    int g = t & 15;
    int p = t >> 4;
    int w = p % WW;
    int t2 = p / WW;
    int h = t2 % HH;
    int n = t2 / HH;
    const int4* src = (const int4*)(x + (size_t)t * 16);
    int4 a = src[0], b = src[1], c = src[2], d = src[3];
    int4 ov;
    ov.x = pack4(a.x, a.y, a.z, a.w);
    ov.y = pack4(b.x, b.y, b.z, b.w);
    ov.z = pack4(c.x, c.y, c.z, c.w);
    ov.w = pack4(d.x, d.y, d.z, d.w);
    size_t dst = (((size_t)n * HP + (h + 1)) * WP + (w + 1)) * CIN + (size_t)g * 16;
    *(int4*)(xp + dst) = ov;
  } else if (bid < 12544 + 576) {
    // pack weight into FRAGMENT order (verified in round 4):
    // (tap, kb, jg) 1024B block; byte at lane l = ((ci>>4)&3)*16 + (cout&15),
    // offset l*16 + (ci&15). A wave's dwordx4 at block + lane*16 is the MFMA B-frag.
    int t = (bid - 12544) * 256 + threadIdx.x;   // 2304*64 threads, 4 ints each
    int i = t * 4;                               // wgt linear int index
    int cout = i / 2304;                         // 2304 ints per cout (9 taps * 256 ci)
    int rem = i - cout * 2304;
    int tap = rem >> 8;
    int ci = rem & 255;                          // 4-aligned
    int4 v = *(const int4*)(wgt + (size_t)i);
    int ov = pack4(v.x, v.y, v.z, v.w);
    int kb = ci >> 6;
    int jg = cout >> 4;
    int l = ((ci >> 4) & 3) * 16 + (cout & 15);
    size_t dst = (((size_t)(tap * 4 + kb) * 16 + jg) * 1024) + (size_t)l * 16 + (ci & 15);
    *(int*)(wp + dst) = ov;
  } else {
    // zero the 1-pixel border of xp
    int t = (bid - 13120) * 256 + threadIdx.x;   // 452*256 threads
    int g = t & 15;
    int pix = t >> 4;                            // 0..7231
    int n = pix / 452;
    int b = pix % 452;
    int h, w;
    if (b < 114) { h = 0; w = b; }
    else if (b < 228) { h = 113; w = b - 114; }
    else { int r = b - 228; h = 1 + (r >> 1); w = (r & 1) ? 113 : 0; }
    size_t dst = (((size_t)n * HP + h) * WP + w) * CIN + (size_t)g * 16;
    *(int4*)(xp + dst) = make_int4(0, 0, 0, 0);
  }
}

// ---------------- implicit-GEMM conv: C[M=200704][256] = A[M][2304] * B[2304][256] ----------------
// BARRIER-FREE design. Tile 128x256, 4 waves (2m x 2n); per wave 64m x 128n = 4x8
// MFMA 16x16x64 i8 (32 MFMA/step, BK=64, 36 steps).
// A: WAVE-PRIVATE LDS. Each wave stages its own 64-row m-half copy (4KB/step,
//    4 buffers = 16KB/wave, 64KB/block), staged 2 steps ahead via global_load_lds.
//    Private staging -> staging wave == reading wave -> NO s_barrier anywhere.
//    (A duplication is L3-absorbed: xp is 51MB << 256MB L3.)
// B: fragment-ordered global->VGPR loads (1KB/wave coalesced dwordx4, L2-resident).
//    Frags 0..3 of step u+1 prefetched during step u (ping-pong bfX/bfY, ~650cy
//    cover); frags 4..7 loaded at step top, covered by the first 16 MFMAs (~326cy).
// Waits: compiler reg-dep vmcnt/lgkm only. A(u)'s LDS visibility at step u is
// implied: A(u) is issued before bhi(u-1) (program order, pinned by one
// sched_barrier(0) per step), and the compiler must retire bhi(u-1) before step
// u-1's second MFMA half -> A(u) retired too. Only manual vmcnt is in the prologue.
__global__ __launch_bounds__(256, 2) void conv_mfma_kernel(const char* __restrict__ xp,
                                                           const char* __restrict__ wp2,
                                                           int* __restrict__ out) {
  __shared__ __align__(16) char As[4 * 16384];   // [wave][buf 0..3][4096]
  const int tid = threadIdx.x;
  const int lane = tid & 63;
  const int wave = tid >> 6;
  const int mtile = blockIdx.x;
  const int wm = wave & 1;   // m half (64 rows)
  const int wn = wave >> 1;  // n half (128 cols)
  char* const myAs = As + wave * 16384;

  // ---- A staging sources: 4 chunks of 1KB per wave per step (wave-private rows) ----
  // LDS tile (per wave, 4KB): [64 rows][4 x 16B], position (r,c) holds global
  // 16B-col (c ^ ((r>>1)&3)). Chunk q covers LDS bytes q*1024 + lane*16.
  const char* gsrcA[4];
#pragma unroll
  for (int q = 0; q < 4; q++) {
    int rl = q * 16 + (lane >> 2);
    int colg = (lane & 3) ^ ((rl >> 1) & 3);
    int m = mtile * 128 + wm * 64 + rl;
    int w = m % WW;
    int t2 = m / WW;
    int h = t2 % HH;
    int n = t2 / HH;
    gsrcA[q] = xp + (((size_t)n * HP + h) * WP + w) * CIN + (size_t)colg * 16;
  }

  // ---- B fragment base: frag j of step s at bptr + s*16384 + j*1024 ----
  const char* bptr = wp2 + (size_t)(wn * 8) * 1024 + (size_t)lane * 16;

  // ---- A fragment LDS offsets (within the wave's 4KB buffer) ----
  int aoff[4];
#pragma unroll
  for (int i = 0; i < 4; i++) {
    int r = i * 16 + (lane & 15);
    aoff[i] = r * 64 + (((lane >> 4) ^ ((r >> 1) & 3)) * 16);
  }

  v4i acc[4][8];
#pragma unroll
  for (int i = 0; i < 4; i++)
#pragma unroll
    for (int j = 0; j < 8; j++) acc[i][j] = (v4i){0, 0, 0, 0};

  v4i bfX[4], bfY[4];   // B frags 0..3 ping-pong (even steps: X, odd: Y)

  // stage A for (tap,kb) global offset AOFF into wave-private buffer b
#define STAGE_A(AOFF, B)                                                     \
  { _Pragma("unroll") for (int q = 0; q < 4; q++)                            \
      load_lds16(gsrcA[q] + (AOFF), myAs + (B) * 4096 + q * 1024); }

  // prologue: A(0)->buf0, bflo(0)->bfX, A(1)->buf1. vmcnt(8) retires A(0) only.
  STAGE_A(0, 0)                              // step 0: tap0 kb0
#pragma unroll
  for (int j = 0; j < 4; j++) bfX[j] = *(const v4i*)(bptr + j * 1024);
  STAGE_A(64, 1)                             // step 1: tap0 kb1
  asm volatile("s_waitcnt vmcnt(8)" ::: "memory");
  __builtin_amdgcn_sched_barrier(0);

// one K-step u: read buf BUF=u%4, B step SB; LO_CUR holds frags0..3(u);
// load bhi=frags4..7(u) now; prefetch LO_NXT=frags0..3(u+1) if DO_LON;
// stage A(u+2) (offset AOFF2 -> buf ABUF2) if DO_AST. No barriers.
#define CONV_STEP(BUF, SB, LO_CUR, LO_NXT, DO_LON, DO_AST, AOFF2, ABUF2)     \
  {                                                                          \
    const char* Ab = myAs + (BUF) * 4096;                                    \
    v4i af[4];                                                               \
    _Pragma("unroll") for (int i = 0; i < 4; i++)                            \
        af[i] = *(const v4i*)(Ab + aoff[i]);                                 \
    v4i bhi[4];                                                              \
    _Pragma("unroll") for (int j = 0; j < 4; j++)                            \
        bhi[j] = *(const v4i*)(bptr + (size_t)(SB) * 16384 + (4 + j) * 1024);\
    if (DO_LON) {                                                            \
      _Pragma("unroll") for (int j = 0; j < 4; j++)                          \
          LO_NXT[j] = *(const v4i*)(bptr + (size_t)((SB) + 1) * 16384 + j * 1024); \
    }                                                                        \
    if (DO_AST) STAGE_A(AOFF2, ABUF2)                                        \
    __builtin_amdgcn_s_setprio(1);                                           \
    _Pragma("unroll") for (int i = 0; i < 4; i++)                            \
      _Pragma("unroll") for (int j = 0; j < 4; j++)                          \
        acc[i][j] = __builtin_amdgcn_mfma_i32_16x16x64_i8(af[i], LO_CUR[j],  \
                                                          acc[i][j], 0, 0, 0); \
    _Pragma("unroll") for (int i = 0; i < 4; i++)                            \
      _Pragma("unroll") for (int j = 0; j < 4; j++)                          \
        acc[i][4 + j] = __builtin_amdgcn_mfma_i32_16x16x64_i8(af[i], bhi[j], \
                                                              acc[i][4 + j], 0, 0, 0); \
    __builtin_amdgcn_s_setprio(0);                                           \
    __builtin_amdgcn_sched_barrier(0);                                       \
  }

  // main loop: groups g=0..7, steps 4g..4g+3; stage A(s+2): taps g(kb2,kb3), g+1(kb0,kb1)
#pragma unroll 1
  for (int g = 0; g < 8; g++) {
    int ky0 = g / 3, kx0 = g - ky0 * 3;
    int oA0 = (ky0 * WP + kx0) * CIN;            // tap g
    int ky1 = (g + 1) / 3, kx1 = (g + 1) - ky1 * 3;
    int oA1 = (ky1 * WP + kx1) * CIN;            // tap g+1
    int sb = 4 * g;
    CONV_STEP(0, sb + 0, bfX, bfY, true, true, oA0 + 128, 2)
    CONV_STEP(1, sb + 1, bfY, bfX, true, true, oA0 + 192, 3)
    CONV_STEP(2, sb + 2, bfX, bfY, true, true, oA1 + 0,   0)
    CONV_STEP(3, sb + 3, bfY, bfX, true, true, oA1 + 64,  1)
  }
  // peeled tail: steps 32..35 (tap 8); A(34),A(35) staged at 32,33
  {
    int oA8 = (2 * WP + 2) * CIN;
    CONV_STEP(0, 32, bfX, bfY, true,  true,  oA8 + 128, 2)
    CONV_STEP(1, 33, bfY, bfX, true,  true,  oA8 + 192, 3)
    CONV_STEP(2, 34, bfX, bfY, true,  false, 0, 0)
    CONV_STEP(3, 35, bfY, bfX, false, false, 0, 0)
  }
#undef CONV_STEP
#undef STAGE_A

  // ---- epilogue: C/D layout col=lane&15, row=(lane>>4)*4+reg ----
#pragma unroll
  for (int i = 0; i < 4; i++) {
    const int mg = mtile * 128 + wm * 64 + i * 16 + ((lane >> 4) * 4);
#pragma unroll
    for (int r = 0; r < 4; r++) {
      int* orow = out + (size_t)(mg + r) * COUT + wn * 128 + (lane & 15);
#pragma unroll
      for (int j = 0; j < 8; j++) orow[j * 16] = acc[i][j][r];
    }
  }
}

// ---------------- fallback (only if ws too small): direct int32 conv ----------------
__global__ void conv_naive_kernel(const int* __restrict__ x, const int* __restrict__ wgt,
                                  int* __restrict__ out, int total) {
  int idx = blockIdx.x * 256 + threadIdx.x;
  if (idx >= total) return;
  int co = idx & 255;
  int p = idx >> 8;
  int w = p % WW;
  int t2 = p / WW;
  int h = t2 % HH;
  int n = t2 / HH;
  int acc = 0;
  for (int ky = 0; ky < 3; ky++) {
    int ih = h + ky - 1;
    if (ih < 0 || ih >= HH) continue;
    for (int kx = 0; kx < 3; kx++) {
      int iw = w + kx - 1;
      if (iw < 0 || iw >= WW) continue;
      const int* xs = x + (((size_t)n * HH + ih) * WW + iw) * CIN;
      const int* ws = wgt + ((size_t)co * 9 + ky * 3 + kx) * CIN;
      for (int ci = 0; ci < CIN; ci++) acc += xs[ci] * ws[ci];
    }
  }
  out[idx] = acc;
}

extern "C" void kernel_launch(void* const* d_in, const int* in_sizes, int n_in,
                              void* d_out, int out_size, void* d_ws, size_t ws_size,
                              hipStream_t stream) {
  const int* x = (const int*)d_in[0];
  const int* wgt = (const int*)d_in[1];
  int* out = (int*)d_out;
  const size_t need = XP_BYTES + WPK_BYTES;
  if (ws_size >= need) {
    char* xp = (char*)d_ws;
    char* wp = xp + XP_BYTES;
    pack_all_kernel<<<13572, 256, 0, stream>>>(x, wgt, xp, wp);
    conv_mfma_kernel<<<M_TOTAL / 128, 256, 0, stream>>>(xp, wp, out);   // 1568 blocks
  } else {
    conv_naive_kernel<<<(out_size + 255) / 256, 256, 0, stream>>>(x, wgt, out, out_size);
  }
}